// Round 11
// baseline (72.608 us; speedup 1.0000x reference)
//
#include <hip/hip_runtime.h>

#define NPTS 8192
#define BLOCK 1024               // 16 waves, 1 block/CU -> 4 waves/SIMD
#define IB 32                    // i-rows per block
#define NBLK (NPTS / IB)         // 256 blocks
#define CH 1024                  // j's per LDS chunk (== BLOCK, 1 embed/thread)
#define NCHK (NPTS / CH)         // 8 chunks
#define CTILES (CH / 16)         // 64 tiles per chunk
#define NW 16                    // waves per block
#define TPWC (CTILES / NW)       // 4 tiles per wave per chunk

typedef __attribute__((ext_vector_type(8))) short bf16x8;
typedef __attribute__((ext_vector_type(4))) float f32x4;
typedef unsigned short u16;
typedef unsigned int u32;

// arg(base2) = C1*(ni+nj) + K2*dot6 ; closeness^2 = exp2(arg)
#define C1f (-144.26950408889634f)   // -100*log2(e)
#define C2f (-28.853900817779268f)   // out = s*exp2(C2*pen)
#define SQK2f (16.98643596886418f)   // sqrt(200*log2(e))
#define SKIP_TH (-50.0f)             // exp2(-50)*8192 ~ 1e-11 penalty err

static __device__ __forceinline__ u16 f2b(float f) {
    union { float f; u32 u; } v; v.f = f;
    u32 u = v.u;
    return (u16)((u + 0x7FFFu + ((u >> 16) & 1u)) >> 16);   // RN-even
}
static __device__ __forceinline__ float b2f(u16 h) {
    union { u32 u; float f; } v; v.u = ((u32)h) << 16;
    return v.f;
}

struct Split { u16 uh[6], ul[6], ch, cm, cl; float sc; };

static __device__ __forceinline__ Split mksplit(
    const float* __restrict__ src, const float* __restrict__ tgt,
    const float* __restrict__ scores, int p)
{
    float x[6];
    x[0] = src[p * 3 + 0]; x[1] = src[p * 3 + 1]; x[2] = src[p * 3 + 2];
    x[3] = tgt[p * 3 + 0]; x[4] = tgt[p * 3 + 1]; x[5] = tgt[p * 3 + 2];
    float n = 0.0f;
    #pragma unroll
    for (int d = 0; d < 6; d++) n += x[d] * x[d];
    float c = C1f * n;
    Split s;
    #pragma unroll
    for (int d = 0; d < 6; d++) {
        float u = SQK2f * x[d];
        u16   h = f2b(u);
        s.uh[d] = h;
        s.ul[d] = f2b(u - b2f(h));
    }
    s.ch = f2b(c);
    float r1 = c - b2f(s.ch);
    s.cm = f2b(r1);
    s.cl = f2b(r1 - b2f(s.cm));
    s.sc = scores[p];
    return s;
}

#define PK(lo, hi) (((u32)(u16)(lo)) | (((u32)(u16)(hi)) << 16))
static __device__ __forceinline__ void emit_a(const Split& s, uint4* da) {
    const u32 one = 0x3F80u;
    da[0] = make_uint4(PK(s.uh[0],s.uh[1]), PK(s.uh[2],s.uh[3]), PK(s.uh[4],s.uh[5]), PK(s.uh[0],s.uh[1]));
    da[1] = make_uint4(PK(s.uh[2],s.uh[3]), PK(s.uh[4],s.uh[5]), PK(s.ul[0],s.ul[1]), PK(s.ul[2],s.ul[3]));
    da[2] = make_uint4(PK(s.ul[4],s.ul[5]), PK(s.ul[0],s.ul[1]), PK(s.ul[2],s.ul[3]), PK(s.ul[4],s.ul[5]));
    da[3] = make_uint4(PK(s.ch, s.cm),      PK(s.cl, one),       PK(one, one),        0u);
}
static __device__ __forceinline__ void emit_b(const Split& s, uint4* db) {
    const u32 one = 0x3F80u;
    db[0] = make_uint4(PK(s.uh[0],s.uh[1]), PK(s.uh[2],s.uh[3]), PK(s.uh[4],s.uh[5]), PK(s.ul[0],s.ul[1]));
    db[1] = make_uint4(PK(s.ul[2],s.ul[3]), PK(s.ul[4],s.ul[5]), PK(s.uh[0],s.uh[1]), PK(s.uh[2],s.uh[3]));
    db[2] = make_uint4(PK(s.uh[4],s.uh[5]), PK(s.ul[0],s.ul[1]), PK(s.ul[2],s.ul[3]), PK(s.ul[4],s.ul[5]));
    db[3] = make_uint4(PK(one, one),        PK(one, s.ch),       PK(s.cm, s.cl),      0u);
}
#undef PK

// LDS B-chunk layout (frag order, conflict-free sequential b128):
// tile tt (16 pts) = 64 uint4; lane l's uint4 at tt*64 + l holds
// B[k=(l>>4)*8 .. +7][j = tt*16 + (l&15)].
// A-frag: A[m][k], m=lane&15, k=(lane>>4)*8+idx. C/D: col=lane&15, row=(lane>>4)*4+r.
__global__ __launch_bounds__(BLOCK, 4) void softnms_kernel(
    const float* __restrict__ src, const float* __restrict__ tgt,
    const float* __restrict__ scores, float* __restrict__ out)
{
    __shared__ uint4 bbuf[2][CTILES * 64];   // 2 x 64 KB
    __shared__ float scj[2][CH];             // 8 KB
    __shared__ uint4 acol[IB * 4];           // 2 KB
    __shared__ float sti[IB];
    __shared__ float red[NW][IB];            // 2 KB

    const int t    = threadIdx.x;
    const int lane = t & 63;
    const int wid  = t >> 6;
    const int half = lane & 15;
    const int quad = lane >> 4;
    const int bx   = blockIdx.x;
    const int i0   = bx * IB;
    const int tl   = t >> 4;                 // local tile this thread embeds
    const int col  = t & 15;

    // ---- prologue: embed own 32 i's + first chunk (rotated start) ----
    if (t < IB) {
        Split s = mksplit(src, tgt, scores, i0 + t);
        emit_a(s, &acol[t * 4]);
        sti[t] = s.sc;
    }
    {
        const int c0 = bx & (NCHK - 1);
        Split s = mksplit(src, tgt, scores, c0 * CH + t);
        uint4 b[4];
        emit_b(s, b);
        #pragma unroll
        for (int q = 0; q < 4; q++)
            bbuf[0][tl * 64 + q * 16 + col] = b[q];
        scj[0][t] = s.sc;
    }
    __syncthreads();

    bf16x8 afrag[2];
    float si[2][4], acc[2][4];
    #pragma unroll
    for (int s = 0; s < 2; s++) {
        afrag[s] = *(const bf16x8*)((const u16*)acol + (s * 16 + half) * 32 + quad * 8);
        #pragma unroll
        for (int r = 0; r < 4; r++) {
            si[s][r]  = sti[s * 16 + quad * 4 + r];
            acc[s][r] = 0.0f;
        }
    }

    const f32x4 zero = {0.0f, 0.0f, 0.0f, 0.0f};

    for (int c = 0; c < NCHK; c++) {
        const int cur = c & 1;
        const int nxt = cur ^ 1;

        // embed next chunk into the idle buffer (rotated order per block
        // to avoid the all-blocks-same-line L2 hotspot seen in R8)
        if (c + 1 < NCHK) {
            const int cc = (c + 1 + bx) & (NCHK - 1);
            Split s = mksplit(src, tgt, scores, cc * CH + t);
            uint4 b[4];
            emit_b(s, b);
            #pragma unroll
            for (int q = 0; q < 4; q++)
                bbuf[nxt][tl * 64 + q * 16 + col] = b[q];
            scj[nxt][t] = s.sc;
        }

        // compute current chunk: 4 tiles per wave, loads issued up front
        bf16x8 bf[TPWC];
        float  sj[TPWC];
        #pragma unroll
        for (int u = 0; u < TPWC; u++) {
            const int lt = wid * TPWC + u;
            bf[u] = *(const bf16x8*)((const u16*)&bbuf[cur][0] + lt * 512 + lane * 8);
            sj[u] = scj[cur][lt * 16 + half];
        }
        #pragma unroll
        for (int u = 0; u < TPWC; u++) {
            f32x4 d0 = __builtin_amdgcn_mfma_f32_16x16x32_bf16(afrag[0], bf[u], zero, 0, 0, 0);
            f32x4 d1 = __builtin_amdgcn_mfma_f32_16x16x32_bf16(afrag[1], bf[u], zero, 0, 0, 0);

            float m0 = fmaxf(fmaxf(d0[0], d0[1]), fmaxf(d0[2], d0[3]));
            if (__any(m0 > SKIP_TH)) {
                #pragma unroll
                for (int r = 0; r < 4; r++) {
                    float e = __builtin_amdgcn_exp2f(d0[r]);
                    acc[0][r] += (sj[u] > si[0][r]) ? e : 0.0f;
                }
            }
            float m1 = fmaxf(fmaxf(d1[0], d1[1]), fmaxf(d1[2], d1[3]));
            if (__any(m1 > SKIP_TH)) {
                #pragma unroll
                for (int r = 0; r < 4; r++) {
                    float e = __builtin_amdgcn_exp2f(d1[r]);
                    acc[1][r] += (sj[u] > si[1][r]) ? e : 0.0f;
                }
            }
        }
        __syncthreads();
    }

    // ---- reduce over 16 j-columns (half bits), then across 16 waves ----
    #pragma unroll
    for (int s = 0; s < 2; s++)
        #pragma unroll
        for (int r = 0; r < 4; r++) {
            float v = acc[s][r];
            v += __shfl_xor(v, 1);
            v += __shfl_xor(v, 2);
            v += __shfl_xor(v, 4);
            v += __shfl_xor(v, 8);
            if (half == 0) red[wid][s * 16 + quad * 4 + r] = v;
        }
    __syncthreads();
    if (t < IB) {
        float p = 0.0f;
        #pragma unroll
        for (int w = 0; w < NW; w++) p += red[w][t];
        out[i0 + t] = sti[t] * __builtin_amdgcn_exp2f(C2f * p);
    }
}

extern "C" void kernel_launch(void* const* d_in, const int* in_sizes, int n_in,
                              void* d_out, int out_size, void* d_ws, size_t ws_size,
                              hipStream_t stream) {
    const float* src    = (const float*)d_in[0];
    const float* tgt    = (const float*)d_in[1];
    const float* scores = (const float*)d_in[2];
    float* out = (float*)d_out;

    softnms_kernel<<<NBLK, BLOCK, 0, stream>>>(src, tgt, scores, out);
}

// Round 12
// 67.180 us; speedup vs baseline: 1.0808x; 1.0808x over previous
//
#include <hip/hip_runtime.h>

#define NPTS 8192
#define BLOCK 1024               // 16 waves, 1 block/CU -> 4 waves/SIMD
#define IB 32                    // i-rows per main block
#define NBLK (NPTS / IB)         // 256 blocks
#define NTILES (NPTS / 16)       // 512 j-tiles
#define NW 16                    // waves per block
#define TPW (NTILES / NW)        // 32 tiles per wave
#define PF 2                     // prefetch distance (L2 latency cover)

typedef __attribute__((ext_vector_type(8))) short bf16x8;
typedef __attribute__((ext_vector_type(4))) float f32x4;
typedef unsigned short u16;
typedef unsigned int u32;

// arg(base2) = C1*(ni+nj) + K2*dot6 ; closeness^2 = exp2(arg)
#define C1f (-144.26950408889634f)   // -100*log2(e)
#define C2f (-28.853900817779268f)   // out = s*exp2(C2*pen)
#define SQK2f (16.98643596886418f)   // sqrt(200*log2(e))
#define SKIP_TH (-50.0f)             // exp2(-50)*8192 ~ 1e-11 penalty err

static __device__ __forceinline__ u16 f2b(float f) {
    union { float f; u32 u; } v; v.f = f;
    u32 u = v.u;
    return (u16)((u + 0x7FFFu + ((u >> 16) & 1u)) >> 16);   // RN-even
}
static __device__ __forceinline__ float b2f(u16 h) {
    union { u32 u; float f; } v; v.u = ((u32)h) << 16;
    return v.f;
}

struct Split { u16 uh[6], ul[6], ch, cm, cl; float sc; };

static __device__ __forceinline__ Split mksplit(
    const float* __restrict__ src, const float* __restrict__ tgt,
    const float* __restrict__ scores, int p)
{
    float x[6];
    x[0] = src[p * 3 + 0]; x[1] = src[p * 3 + 1]; x[2] = src[p * 3 + 2];
    x[3] = tgt[p * 3 + 0]; x[4] = tgt[p * 3 + 1]; x[5] = tgt[p * 3 + 2];
    float n = 0.0f;
    #pragma unroll
    for (int d = 0; d < 6; d++) n += x[d] * x[d];
    float c = C1f * n;
    Split s;
    #pragma unroll
    for (int d = 0; d < 6; d++) {
        float u = SQK2f * x[d];
        u16   h = f2b(u);
        s.uh[d] = h;
        s.ul[d] = f2b(u - b2f(h));
    }
    s.ch = f2b(c);
    float r1 = c - b2f(s.ch);
    s.cm = f2b(r1);
    s.cl = f2b(r1 - b2f(s.cm));
    s.sc = scores[p];
    return s;
}

#define PK(lo, hi) (((u32)(u16)(lo)) | (((u32)(u16)(hi)) << 16))
static __device__ __forceinline__ void emit_a(const Split& s, uint4* da) {
    const u32 one = 0x3F80u;
    da[0] = make_uint4(PK(s.uh[0],s.uh[1]), PK(s.uh[2],s.uh[3]), PK(s.uh[4],s.uh[5]), PK(s.uh[0],s.uh[1]));
    da[1] = make_uint4(PK(s.uh[2],s.uh[3]), PK(s.uh[4],s.uh[5]), PK(s.ul[0],s.ul[1]), PK(s.ul[2],s.ul[3]));
    da[2] = make_uint4(PK(s.ul[4],s.ul[5]), PK(s.ul[0],s.ul[1]), PK(s.ul[2],s.ul[3]), PK(s.ul[4],s.ul[5]));
    da[3] = make_uint4(PK(s.ch, s.cm),      PK(s.cl, one),       PK(one, one),        0u);
}
static __device__ __forceinline__ void emit_b(const Split& s, uint4* db) {
    const u32 one = 0x3F80u;
    db[0] = make_uint4(PK(s.uh[0],s.uh[1]), PK(s.uh[2],s.uh[3]), PK(s.uh[4],s.uh[5]), PK(s.ul[0],s.ul[1]));
    db[1] = make_uint4(PK(s.ul[2],s.ul[3]), PK(s.ul[4],s.ul[5]), PK(s.uh[0],s.uh[1]), PK(s.uh[2],s.uh[3]));
    db[2] = make_uint4(PK(s.uh[4],s.uh[5]), PK(s.ul[0],s.ul[1]), PK(s.ul[2],s.ul[3]), PK(s.ul[4],s.ul[5]));
    db[3] = make_uint4(PK(one, one),        PK(one, s.ch),       PK(s.cm, s.cl),      0u);
}
#undef PK

// Fragment-order tables: tile tt (16 points) occupies 1024 B; lane l's 16 B at
// tt*1024 + l*16 holds column[k = (l>>4)*8 .. +7][pt = tt*16 + (l&15)].
__global__ __launch_bounds__(512) void prep_kernel(
    const float* __restrict__ src, const float* __restrict__ tgt,
    const float* __restrict__ scores,
    u16* __restrict__ Ag, u16* __restrict__ Bg)
{
    const int p = blockIdx.x * 512 + threadIdx.x;
    Split s = mksplit(src, tgt, scores, p);
    uint4 a[4], b[4];
    emit_a(s, a);
    emit_b(s, b);
    uint4* Ag4 = (uint4*)Ag;
    uint4* Bg4 = (uint4*)Bg;
    const int base = (p >> 4) * 64 + (p & 15);
    #pragma unroll
    for (int q = 0; q < 4; q++) {
        Ag4[base + q * 16] = a[q];
        Bg4[base + q * 16] = b[q];
    }
}

// A-frag: A[m][k], m=lane&15, k=(lane>>4)*8+idx. C/D: col=lane&15, row=(lane>>4)*4+r.
// 16 waves/block (1 block/CU -> 4 waves/SIMD). Per-block stagger spreads the
// 4096 waves across the 512 tiles (anti L2-hotspot, R9 win). Prefetch
// distance 2 keeps ~2 L2 loads in flight across the branchy epilogue (R12).
__global__ __launch_bounds__(BLOCK, 4) void main_kernel(
    const u16* __restrict__ Ag, const u16* __restrict__ Bg,
    const float* __restrict__ scores, float* __restrict__ out)
{
    __shared__ float red[NW][IB];

    const int t    = threadIdx.x;
    const int lane = t & 63;
    const int wid  = t >> 6;
    const int half = lane & 15;
    const int quad = lane >> 4;
    const int bx   = blockIdx.x;
    const int i0   = bx * IB;

    const int wgrp  = (wid + bx) & (NW - 1);     // staggered wave-group
    const int phase = (bx >> 4) & (TPW - 1);     // staggered start phase

    bf16x8 afrag[2];
    float si[2][4], acc[2][4];
    #pragma unroll
    for (int s = 0; s < 2; s++) {
        afrag[s] = *(const bf16x8*)(Ag + (size_t)(bx * 2 + s) * 512 + lane * 8);
        #pragma unroll
        for (int r = 0; r < 4; r++) {
            si[s][r]  = scores[i0 + s * 16 + quad * 4 + r];
            acc[s][r] = 0.0f;
        }
    }

    const f32x4 zero = {0.0f, 0.0f, 0.0f, 0.0f};

    // prefetch pipeline, depth PF=2
    bf16x8 bpf[PF];
    float  spf[PF];
    #pragma unroll
    for (int q = 0; q < PF; q++) {
        const int tq = wgrp * TPW + ((q + phase) & (TPW - 1));
        bpf[q] = *(const bf16x8*)(Bg + (size_t)tq * 512 + lane * 8);
        spf[q] = scores[tq * 16 + half];
    }

    #pragma unroll 4
    for (int u = 0; u < TPW; u++) {
        bf16x8 bfrag = bpf[0];
        float  sj    = spf[0];
        #pragma unroll
        for (int q = 0; q < PF - 1; q++) { bpf[q] = bpf[q + 1]; spf[q] = spf[q + 1]; }
        // issue next prefetch (wraps at end; harmless)
        const int tn = wgrp * TPW + ((u + PF + phase) & (TPW - 1));
        bpf[PF - 1] = *(const bf16x8*)(Bg + (size_t)tn * 512 + lane * 8);
        spf[PF - 1] = scores[tn * 16 + half];

        f32x4 d0 = __builtin_amdgcn_mfma_f32_16x16x32_bf16(afrag[0], bfrag, zero, 0, 0, 0);
        f32x4 d1 = __builtin_amdgcn_mfma_f32_16x16x32_bf16(afrag[1], bfrag, zero, 0, 0, 0);

        float m0 = fmaxf(fmaxf(d0[0], d0[1]), fmaxf(d0[2], d0[3]));
        if (__any(m0 > SKIP_TH)) {
            #pragma unroll
            for (int r = 0; r < 4; r++) {
                float e = __builtin_amdgcn_exp2f(d0[r]);
                acc[0][r] += (sj > si[0][r]) ? e : 0.0f;
            }
        }
        float m1 = fmaxf(fmaxf(d1[0], d1[1]), fmaxf(d1[2], d1[3]));
        if (__any(m1 > SKIP_TH)) {
            #pragma unroll
            for (int r = 0; r < 4; r++) {
                float e = __builtin_amdgcn_exp2f(d1[r]);
                acc[1][r] += (sj > si[1][r]) ? e : 0.0f;
            }
        }
    }

    // reduce over 16 j-columns (half bits), then across 16 waves
    #pragma unroll
    for (int s = 0; s < 2; s++)
        #pragma unroll
        for (int r = 0; r < 4; r++) {
            float v = acc[s][r];
            v += __shfl_xor(v, 1);
            v += __shfl_xor(v, 2);
            v += __shfl_xor(v, 4);
            v += __shfl_xor(v, 8);
            if (half == 0) red[wid][s * 16 + quad * 4 + r] = v;
        }
    __syncthreads();
    if (t < IB) {
        float p = 0.0f;
        #pragma unroll
        for (int w = 0; w < NW; w++) p += red[w][t];
        out[i0 + t] = scores[i0 + t] * __builtin_amdgcn_exp2f(C2f * p);
    }
}

extern "C" void kernel_launch(void* const* d_in, const int* in_sizes, int n_in,
                              void* d_out, int out_size, void* d_ws, size_t ws_size,
                              hipStream_t stream) {
    const float* src    = (const float*)d_in[0];
    const float* tgt    = (const float*)d_in[1];
    const float* scores = (const float*)d_in[2];
    float* out = (float*)d_out;

    u16* Ag = (u16*)d_ws;                        // 512 KB, fragment-ordered
    u16* Bg = (u16*)((char*)d_ws + 524288);      // 512 KB, fragment-ordered

    prep_kernel<<<NPTS / 512, 512, 0, stream>>>(src, tgt, scores, Ag, Bg);
    main_kernel<<<NBLK, BLOCK, 0, stream>>>(Ag, Bg, scores, out);
}